// Round 13
// baseline (747.221 us; speedup 1.0000x reference)
//
#include <hip/hip_runtime.h>
#include <hip/hip_bf16.h>

namespace {

typedef _Float16 h16;
typedef _Float16 f16x8 __attribute__((ext_vector_type(8)));
typedef _Float16 f16x4 __attribute__((ext_vector_type(4)));
typedef float    f32x4 __attribute__((ext_vector_type(4)));
typedef unsigned long long u64;

constexpr int T_SEQ = 512;
constexpr int B_SZ  = 1024;
constexpr int H_DIM = 128;
constexpr int ROWS  = 16;           // batch rows per group (MFMA N-tile)
constexpr int NT    = 512;          // 8 waves
constexpr int NGRP  = B_SZ / ROWS;  // 64 groups -> 128 blocks
constexpr int CHUNK = 32;           // steps per producer->consumer handoff

// r12 cross-block pipeline (659us, verified) + r10 frag-major LDS layout
// (verified conflict-free: 17.8M -> 2.1M). Slot = one f16x8 (16B) = one
// lane's MFMA B-frag chunk; reads are lane-linear 1KB contiguous.
// Producer block g: layer-0, publishes h1(t) (8B relaxed agent atomics,
// frag-compatible [t][b][unit] format); fence+release flag every CHUNK.
// Consumer block g: layer-1, chunk-gated spin, 1-step h1 prefetch staged
// directly into frag-major slots. __launch_bounds__(NT,1) -> 128 distinct CUs.
// Frag algebra verified rounds 10/11 (identical absmax):
//  element (batch=lr, dims j0..j0+3):
//   slotH = (wv>>1)*64 + ((wv&1)*2 + (q>>1))*16 + lr,  e0 = (q&1)*4
template <int INDIM, bool PROD>
__device__ void gru_body(h16* lds,
                         const float* __restrict__ xin,
                         const float* __restrict__ w_ih,
                         const float* __restrict__ w_hh,
                         const float* __restrict__ b_ih,
                         const float* __restrict__ b_hh,
                         u64* __restrict__ h1q,    // [T][B][32] u64
                         int* __restrict__ flag,   // this group's chunk count
                         float* __restrict__ h2out,
                         const int g)
{
  constexpr int CHH = H_DIM / 32;    // 4 chunks over h-state
  constexpr int CXX = INDIM / 32;    // 2 (l0) / 4 (l1) chunks over input
  constexpr int FH  = 0;             // h-state frags [2][CHH][64]
  constexpr int FI  = 2 * CHH * 64;  // input frags   [2][CXX][64]

  const int tid = threadIdx.x;
  const int wv  = tid >> 6;
  const int ln  = tid & 63;
  const int q   = ln >> 4;
  const int lr  = ln & 15;
  const int r0  = g * ROWS;
  const int j0  = wv * 16 + q * 4;

  const int slotH = (wv >> 1) * 64 + ((wv & 1) * 2 + (q >> 1)) * 16 + lr;
  const int e0    = (q & 1) * 4;

  auto ldw = [](const float* pw) {
    const float4 v0 = *(const float4*)(pw);
    const float4 v1 = *(const float4*)(pw + 4);
    f16x8 f;
    f[0]=(h16)v0.x; f[1]=(h16)v0.y; f[2]=(h16)v0.z; f[3]=(h16)v0.w;
    f[4]=(h16)v1.x; f[5]=(h16)v1.y; f[6]=(h16)v1.z; f[7]=(h16)v1.w;
    return f;
  };

  // ---- weights -> fp16 frags (rounds 4-12 verified layout) ----
  f16x8 wA[3][CHH], wB[3][CXX];
  #pragma unroll
  for (int p = 0; p < 3; ++p) {
    const int gr = p * H_DIM + wv * 16 + lr;
    #pragma unroll
    for (int ks = 0; ks < CHH; ++ks)
      wA[p][ks] = ldw(w_hh + (size_t)gr * H_DIM + ks * 32 + q * 8);
    #pragma unroll
    for (int ks = 0; ks < CXX; ++ks)
      wB[p][ks] = ldw(w_ih + (size_t)gr * INDIM + ks * 32 + q * 8);
  }

  // ---- biases folded into MFMA C-init ----
  f32x4 bR, bZ, bNx, bNh;
  {
    const float4 ir  = *(const float4*)&b_ih[j0];
    const float4 hr  = *(const float4*)&b_hh[j0];
    const float4 iz  = *(const float4*)&b_ih[H_DIM + j0];
    const float4 hz  = *(const float4*)&b_hh[H_DIM + j0];
    const float4 in_ = *(const float4*)&b_ih[2 * H_DIM + j0];
    const float4 hn  = *(const float4*)&b_hh[2 * H_DIM + j0];
    bR[0]=ir.x+hr.x; bR[1]=ir.y+hr.y; bR[2]=ir.z+hr.z; bR[3]=ir.w+hr.w;
    bZ[0]=iz.x+hz.x; bZ[1]=iz.y+hz.y; bZ[2]=iz.z+hz.z; bZ[3]=iz.w+hz.w;
    bNx[0]=in_.x; bNx[1]=in_.y; bNx[2]=in_.z; bNx[3]=in_.w;
    bNh[0]=hn.x;  bNh[1]=hn.y;  bNh[2]=hn.z;  bNh[3]=hn.w;
  }

  auto rd = [&](int cb) { return *(const f16x8*)&lds[(cb + ln) * 8]; };

  // ---- staging ids ----
  // producer (x, CXX=2): tid<128, sc=tid>>6 in {0,1}, sl=tid&63
  // consumer (h1, CXX=4): tid<256, sc=tid>>6 in {0..3}, sl=tid&63
  const int  sc  = (tid >> 6) & 3;
  const int  sl  = tid & 63;
  const bool stg = (tid < CXX * 64);
  const size_t xrow = (size_t)(r0 + (sl & 15)) * T_SEQ;   // producer only
  const int    xk   = (sl >> 4) * 8 + sc * 32;

  auto load_x = [&](int t, f16x8& d) {     // producer: x f32 -> f16 frag
    if (stg) {
      const float* p = xin + (xrow + t) * 64 + xk;
      const float4 v0 = *(const float4*)(p);
      const float4 v1 = *(const float4*)(p + 4);
      d[0]=(h16)v0.x; d[1]=(h16)v0.y; d[2]=(h16)v0.z; d[3]=(h16)v0.w;
      d[4]=(h16)v1.x; d[5]=(h16)v1.y; d[6]=(h16)v1.z; d[7]=(h16)v1.w;
    }
  };
  auto load_h1 = [&](int t, f16x8& d) {    // consumer: two 8B units = one frag
    if (stg) {
      const size_t base = ((size_t)t * B_SZ + r0 + (sl & 15)) * 32 + sc * 8 + (sl >> 4) * 2;
      const u64 b0 = __hip_atomic_load(&h1q[base],     __ATOMIC_RELAXED, __HIP_MEMORY_SCOPE_AGENT);
      const u64 b1 = __hip_atomic_load(&h1q[base + 1], __ATOMIC_RELAXED, __HIP_MEMORY_SCOPE_AGENT);
      __builtin_memcpy(&d,                  &b0, 8);
      __builtin_memcpy((char*)&d + 8,       &b1, 8);
    }
  };
  auto stage_in = [&](int buf, const f16x8& s) {
    if (stg) *(f16x8*)&lds[(FI + buf * CXX * 64 + sc * 64 + sl) * 8] = s;
  };

  // ---- prologue: zero h-state frags buf0 (512 slots / 512 threads) ----
  {
    f16x8 z; z[0]=z[1]=z[2]=z[3]=z[4]=z[5]=z[6]=z[7] = (h16)0.f;
    if (tid < 2 * CHH * 64 / 2) *(f16x8*)&lds[(FH + tid % 256) * 8] = z;  // buf0: slots 0..255
  }
  f16x4 h_old; h_old[0]=h_old[1]=h_old[2]=h_old[3] = (h16)0.f;

  f16x8 sA, sB;
  if constexpr (PROD) {
    f16x8 s0; load_x(0, s0); stage_in(0, s0);
    load_x(1, sA);
  } else {
    while (__hip_atomic_load(flag, __ATOMIC_ACQUIRE, __HIP_MEMORY_SCOPE_AGENT) < 1)
      __builtin_amdgcn_s_sleep(2);
    f16x8 s0; load_h1(0, s0); stage_in(0, s0);
  }
  __syncthreads();

  auto gates = [&](const f32x4& aR, const f32x4& aZ, const f32x4& aNx2, const f32x4& aNh2,
                   f16x4& nv4, float* hnv) {
    #pragma unroll
    for (int i = 0; i < 4; ++i) {
      const float rg = __builtin_amdgcn_rcpf(1.f + __expf(-aR[i]));
      const float zg = __builtin_amdgcn_rcpf(1.f + __expf(-aZ[i]));
      const float na = aNx2[i] + rg * aNh2[i];
      const float e2 = __expf(2.f * na);
      const float ng = 1.f - 2.f * __builtin_amdgcn_rcpf(e2 + 1.f);
      const float ho = (float)h_old[i];
      const float hn = ng + zg * (ho - ng);
      hnv[i] = hn;
      nv4[i] = (h16)hn;
    }
    h_old = nv4;
  };

  auto mfma_all = [&](const f16x8* bh, const f16x8* bx,
                      f32x4& aR, f32x4& aZ, f32x4& aNh2, f32x4& aNx2) {
    aR = bR; aZ = bZ; aNh2 = bNh; aNx2 = bNx;
    #pragma unroll
    for (int ks = 0; ks < CHH; ++ks) {
      aR   = __builtin_amdgcn_mfma_f32_16x16x32_f16(wA[0][ks], bh[ks], aR, 0, 0, 0);
      aZ   = __builtin_amdgcn_mfma_f32_16x16x32_f16(wA[1][ks], bh[ks], aZ, 0, 0, 0);
      aNh2 = __builtin_amdgcn_mfma_f32_16x16x32_f16(wA[2][ks], bh[ks], aNh2, 0, 0, 0);
    }
    #pragma unroll
    for (int ks = 0; ks < CXX; ++ks) {
      aR   = __builtin_amdgcn_mfma_f32_16x16x32_f16(wB[0][ks], bx[ks], aR, 0, 0, 0);
      aZ   = __builtin_amdgcn_mfma_f32_16x16x32_f16(wB[1][ks], bx[ks], aZ, 0, 0, 0);
      aNx2 = __builtin_amdgcn_mfma_f32_16x16x32_f16(wB[2][ks], bx[ks], aNx2, 0, 0, 0);
    }
  };

  if constexpr (PROD) {
    auto pstep = [&](int t, int cur, f16x8& s_use, f16x8& s_load) {
      f16x8 bh[CHH], bx[CXX];
      #pragma unroll
      for (int ks = 0; ks < CHH; ++ks) bh[ks] = rd(FH + cur * CHH * 64 + ks * 64);
      #pragma unroll
      for (int ks = 0; ks < CXX; ++ks) bx[ks] = rd(FI + cur * CXX * 64 + ks * 64);

      load_x((t + 2 < T_SEQ) ? t + 2 : T_SEQ - 1, s_load);

      f32x4 aR, aZ, aNh2, aNx2;
      mfma_all(bh, bx, aR, aZ, aNh2, aNx2);

      f16x4 nv4; float hnv[4];
      gates(aR, aZ, aNx2, aNh2, nv4, hnv);

      u64 bits; __builtin_memcpy(&bits, &nv4, 8);
      __hip_atomic_store(&h1q[((size_t)t * B_SZ + r0 + lr) * 32 + (j0 >> 2)], bits,
                         __ATOMIC_RELAXED, __HIP_MEMORY_SCOPE_AGENT);

      *(f16x4*)&lds[(FH + (cur ^ 1) * CHH * 64 + slotH) * 8 + e0] = nv4;
      stage_in(cur ^ 1, s_use);

      if ((t & (CHUNK - 1)) == CHUNK - 1) __threadfence();  // once per chunk
      __syncthreads();
      if (((t & (CHUNK - 1)) == CHUNK - 1) && tid == 0)
        __hip_atomic_store(flag, (t + 1) / CHUNK, __ATOMIC_RELEASE, __HIP_MEMORY_SCOPE_AGENT);
    };

    #pragma unroll 1
    for (int t = 0; t < T_SEQ; t += 2) {
      pstep(t,     0, sA, sB);
      pstep(t + 1, 1, sB, sA);
    }
  } else {
    #pragma unroll 1
    for (int t = 0; t < T_SEQ; ++t) {
      const int cur = t & 1;
      f16x8 bh[CHH], bx[CXX];
      #pragma unroll
      for (int ks = 0; ks < CHH; ++ks) bh[ks] = rd(FH + cur * CHH * 64 + ks * 64);
      #pragma unroll
      for (int ks = 0; ks < CXX; ++ks) bx[ks] = rd(FI + cur * CXX * 64 + ks * 64);

      // prefetch h1(t+1): chunk-gated spin only at 32-step boundaries
      f16x8 sN;
      const bool have = (t + 1 < T_SEQ);
      if (have) {
        if (((t + 1) & (CHUNK - 1)) == 0) {
          const int need = (t + 1) / CHUNK + 1;
          while (__hip_atomic_load(flag, __ATOMIC_ACQUIRE, __HIP_MEMORY_SCOPE_AGENT) < need)
            __builtin_amdgcn_s_sleep(2);
        }
        load_h1(t + 1, sN);
      }

      f32x4 aR, aZ, aNh2, aNx2;
      mfma_all(bh, bx, aR, aZ, aNh2, aNx2);

      f16x4 nv4; float hnv[4];
      gates(aR, aZ, aNx2, aNh2, nv4, hnv);

      *(f16x4*)&lds[(FH + (cur ^ 1) * CHH * 64 + slotH) * 8 + e0] = nv4;
      if (have) stage_in(cur ^ 1, sN);
      if (t == T_SEQ - 1)
        *(float4*)&h2out[(size_t)(r0 + lr) * H_DIM + j0] =
            make_float4(hnv[0], hnv[1], hnv[2], hnv[3]);
      __syncthreads();
    }
  }
}

__global__ __launch_bounds__(NT, 1)   // 1 block/CU: producers & consumers on distinct CUs
void gru_fused(const float* __restrict__ x,
               const float* __restrict__ w_ih0, const float* __restrict__ w_hh0,
               const float* __restrict__ b_ih0, const float* __restrict__ b_hh0,
               const float* __restrict__ w_ih1, const float* __restrict__ w_hh1,
               const float* __restrict__ b_ih1, const float* __restrict__ b_hh1,
               u64* __restrict__ h1q, int* __restrict__ flags, float* __restrict__ h2)
{
  // consumer needs (2*4 + 2*4)*64 slots * 16B = 16 KB (producer: 12 KB)
  __shared__ __align__(16) h16 lds[1024 * 8];
  const int bid = blockIdx.x;
  if (bid < NGRP)
    gru_body<64, true>(lds, x, w_ih0, w_hh0, b_ih0, b_hh0, h1q, &flags[bid], nullptr, bid);
  else
    gru_body<128, false>(lds, nullptr, w_ih1, w_hh1, b_ih1, b_hh1, h1q,
                         &flags[bid - NGRP], h2, bid - NGRP);
}

// FC head: out = fc2( BN( relu( fc1(h2_last) ) ) ); one row per block.
__global__ __launch_bounds__(64)
void head_kernel(const float* __restrict__ h2,
                 const float* __restrict__ fc1_w, const float* __restrict__ fc1_b,
                 const float* __restrict__ fc2_w, const float* __restrict__ fc2_b,
                 const float* __restrict__ gamma, const float* __restrict__ beta,
                 const float* __restrict__ mean,  const float* __restrict__ var,
                 float* __restrict__ out)
{
  const int row = blockIdx.x;
  const int j   = threadIdx.x;
  __shared__ __align__(16) float hrow[H_DIM];
  __shared__ __align__(16) float act[64];

  hrow[j]      = h2[(size_t)row * H_DIM + j];
  hrow[64 + j] = h2[(size_t)row * H_DIM + 64 + j];
  __syncthreads();

  float s = fc1_b[j];
  const float4* wr = reinterpret_cast<const float4*>(fc1_w + (size_t)j * H_DIM);
  #pragma unroll
  for (int k4 = 0; k4 < H_DIM / 4; ++k4) {
    const float4 w = wr[k4];
    const float4 h = reinterpret_cast<const float4*>(hrow)[k4];
    s += w.x * h.x + w.y * h.y + w.z * h.z + w.w * h.w;
  }
  s = fmaxf(s, 0.f);
  s = (s - mean[j]) * rsqrtf(var[j] + 1e-5f) * gamma[j] + beta[j];
  act[j] = s;
  __syncthreads();

  if (j < 2) {
    float o = fc2_b[j];
    #pragma unroll
    for (int k = 0; k < 64; ++k) o += fc2_w[(size_t)j * 64 + k] * act[k];
    out[(size_t)row * 2 + j] = o;
  }
}

} // namespace

extern "C" void kernel_launch(void* const* d_in, const int* in_sizes, int n_in,
                              void* d_out, int out_size, void* d_ws, size_t ws_size,
                              hipStream_t stream) {
  const float* x     = (const float*)d_in[0];
  const float* w_ih0 = (const float*)d_in[1];
  const float* w_hh0 = (const float*)d_in[2];
  const float* b_ih0 = (const float*)d_in[3];
  const float* b_hh0 = (const float*)d_in[4];
  const float* w_ih1 = (const float*)d_in[5];
  const float* w_hh1 = (const float*)d_in[6];
  const float* b_ih1 = (const float*)d_in[7];
  const float* b_hh1 = (const float*)d_in[8];
  const float* fc1_w = (const float*)d_in[9];
  const float* fc1_b = (const float*)d_in[10];
  const float* fc2_w = (const float*)d_in[11];
  const float* fc2_b = (const float*)d_in[12];
  const float* gamma = (const float*)d_in[13];
  const float* beta  = (const float*)d_in[14];
  const float* mean  = (const float*)d_in[15];
  const float* var   = (const float*)d_in[16];
  float* out = (float*)d_out;

  char* ws = (char*)d_ws;
  const size_t h2_bytes = (size_t)B_SZ * H_DIM * sizeof(float);            // 512 KB
  const size_t h1_bytes = (size_t)T_SEQ * B_SZ * H_DIM * sizeof(h16);      // 134 MB
  const size_t fl_bytes = (size_t)NGRP * sizeof(int);
  if (ws_size < h2_bytes + h1_bytes + fl_bytes) return;  // fail visibly

  float* h2    = (float*)ws;
  u64*   h1q   = (u64*)(ws + h2_bytes);
  int*   flags = (int*)(ws + h2_bytes + h1_bytes);

  hipMemsetAsync(flags, 0, fl_bytes, stream);   // flags start at 0 each replay
  gru_fused<<<dim3(2 * NGRP), dim3(NT), 0, stream>>>(
      x, w_ih0, w_hh0, b_ih0, b_hh0, w_ih1, w_hh1, b_ih1, b_hh1, h1q, flags, h2);
  head_kernel<<<dim3(B_SZ), dim3(64), 0, stream>>>(
      h2, fc1_w, fc1_b, fc2_w, fc2_b, gamma, beta, mean, var, out);
}

// Round 14
// 663.719 us; speedup vs baseline: 1.1258x; 1.1258x over previous
//
#include <hip/hip_runtime.h>
#include <hip/hip_bf16.h>

namespace {

typedef _Float16 h16;
typedef _Float16 f16x8 __attribute__((ext_vector_type(8)));
typedef _Float16 f16x4 __attribute__((ext_vector_type(4)));
typedef _Float16 f16x2 __attribute__((ext_vector_type(2)));
typedef float    f32x4 __attribute__((ext_vector_type(4)));
typedef unsigned long long u64;

constexpr int T_SEQ = 512;
constexpr int B_SZ  = 1024;
constexpr int H_DIM = 128;
constexpr int ROWS  = 16;           // batch rows per group (MFMA N-tile)
constexpr int NT    = 512;          // 8 waves
constexpr int NGRP  = B_SZ / ROWS;  // 64 groups -> 128 blocks
constexpr int CHUNK = 32;           // steps per producer->consumer handoff

// r12 structure exactly (659us best; r13 proved global coalescing beats LDS
// conflict elimination here) + two additions:
//  - consumer h1 prefetch 2 steps deep (ping-pong regs, covers cross-XCD lat)
//  - FC head fused into the consumer's final step (head launch + h2 HBM
//    round-trip deleted)
template <int INDIM, bool PROD>
__device__ void gru_body(char* smem_raw, float* headbuf,
                         const float* __restrict__ xin,
                         const float* __restrict__ w_ih,
                         const float* __restrict__ w_hh,
                         const float* __restrict__ b_ih,
                         const float* __restrict__ b_hh,
                         u64* __restrict__ h1q,    // [T][B][32] u64
                         int* __restrict__ flag,   // this group's chunk count
                         const float* __restrict__ fc1_w,
                         const float* __restrict__ fc1_b,
                         const float* __restrict__ fc2_w,
                         const float* __restrict__ fc2_b,
                         const float* __restrict__ gamma,
                         const float* __restrict__ beta,
                         const float* __restrict__ mean,
                         const float* __restrict__ var,
                         float* __restrict__ out,  // [B][2]
                         const int g)
{
  constexpr int KSH  = H_DIM / 32;
  constexpr int KSX  = INDIM / 32;
  constexpr int ROWP = H_DIM + INDIM + 8;   // r5/r12-proven pad (16B-aligned rows)

  auto hx = reinterpret_cast<h16 (*)[ROWS][ROWP]>(smem_raw);

  const int tid = threadIdx.x;
  const int wv  = tid >> 6;
  const int ln  = tid & 63;
  const int q   = ln >> 4;
  const int lr  = ln & 15;
  const int r0  = g * ROWS;
  const int j0  = wv * 16 + q * 4;

  // ---- weights -> fp16 frags (rounds 4-12 verified layout) ----
  f16x8 wA[3][KSH], wB[3][KSX];
  #pragma unroll
  for (int p = 0; p < 3; ++p) {
    const int gr = p * H_DIM + wv * 16 + lr;
    #pragma unroll
    for (int ks = 0; ks < KSH; ++ks) {
      const float* pw = w_hh + (size_t)gr * H_DIM + ks * 32 + q * 8;
      const float4 v0 = *(const float4*)(pw);
      const float4 v1 = *(const float4*)(pw + 4);
      f16x8 f;
      f[0]=(h16)v0.x; f[1]=(h16)v0.y; f[2]=(h16)v0.z; f[3]=(h16)v0.w;
      f[4]=(h16)v1.x; f[5]=(h16)v1.y; f[6]=(h16)v1.z; f[7]=(h16)v1.w;
      wA[p][ks] = f;
    }
    #pragma unroll
    for (int ks = 0; ks < KSX; ++ks) {
      const float* pw = w_ih + (size_t)gr * INDIM + ks * 32 + q * 8;
      const float4 v0 = *(const float4*)(pw);
      const float4 v1 = *(const float4*)(pw + 4);
      f16x8 f;
      f[0]=(h16)v0.x; f[1]=(h16)v0.y; f[2]=(h16)v0.z; f[3]=(h16)v0.w;
      f[4]=(h16)v1.x; f[5]=(h16)v1.y; f[6]=(h16)v1.z; f[7]=(h16)v1.w;
      wB[p][ks] = f;
    }
  }

  // ---- biases folded into MFMA C-init ----
  f32x4 bR, bZ, bNx, bNh;
  {
    const float4 ir  = *(const float4*)&b_ih[j0];
    const float4 hr  = *(const float4*)&b_hh[j0];
    const float4 iz  = *(const float4*)&b_ih[H_DIM + j0];
    const float4 hz  = *(const float4*)&b_hh[H_DIM + j0];
    const float4 in_ = *(const float4*)&b_ih[2 * H_DIM + j0];
    const float4 hn  = *(const float4*)&b_hh[2 * H_DIM + j0];
    bR[0]=ir.x+hr.x; bR[1]=ir.y+hr.y; bR[2]=ir.z+hr.z; bR[3]=ir.w+hr.w;
    bZ[0]=iz.x+hz.x; bZ[1]=iz.y+hz.y; bZ[2]=iz.z+hz.z; bZ[3]=iz.w+hz.w;
    bNx[0]=in_.x; bNx[1]=in_.y; bNx[2]=in_.z; bNx[3]=in_.w;
    bNh[0]=hn.x;  bNh[1]=hn.y;  bNh[2]=hn.z;  bNh[3]=hn.w;
  }

  const int sr = tid >> 5;   // 0..15
  const int si = tid & 31;   // 0..31

  // ---- prologue: zero h-state in buf0 ----
  {
    f16x4 z; z[0]=z[1]=z[2]=z[3] = (h16)0.f;
    *(f16x4*)&hx[0][sr][si * 4] = z;
  }
  f16x4 h_old; h_old[0]=h_old[1]=h_old[2]=h_old[3] = (h16)0.f;

  auto load_h1 = [&](int t, f16x4& d) {   // consumer: coalesced 8B/lane
    const u64 bits = __hip_atomic_load(&h1q[((size_t)t * B_SZ + r0 + sr) * 32 + si],
                                       __ATOMIC_RELAXED, __HIP_MEMORY_SCOPE_AGENT);
    __builtin_memcpy(&d, &bits, 8);
  };

  f16x2 sA, sB;          // producer x ping-pong
  f16x4 cA, cB;          // consumer h1 ping-pong (2-deep)
  if constexpr (PROD) {
    const float2 v0 = *(const float2*)(xin + ((size_t)(r0 + sr) * T_SEQ + 0) * 64 + si * 2);
    f16x2 s0; s0[0] = (h16)v0.x; s0[1] = (h16)v0.y;
    *(f16x2*)&hx[0][sr][H_DIM + si * 2] = s0;
    const float2 v1 = *(const float2*)(xin + ((size_t)(r0 + sr) * T_SEQ + 1) * 64 + si * 2);
    sA[0] = (h16)v1.x; sA[1] = (h16)v1.y;
  } else {
    while (__hip_atomic_load(flag, __ATOMIC_ACQUIRE, __HIP_MEMORY_SCOPE_AGENT) < 1)
      __builtin_amdgcn_s_sleep(2);
    f16x4 s0; load_h1(0, s0);
    *(f16x4*)&hx[0][sr][H_DIM + si * 4] = s0;
    load_h1(1, cA);                       // 2-deep prologue
  }
  __syncthreads();

  auto gates = [&](const f32x4& aR, const f32x4& aZ, const f32x4& aNx2, const f32x4& aNh2,
                   f16x4& nv4, float* hnv) {
    #pragma unroll
    for (int i = 0; i < 4; ++i) {
      const float rg = __builtin_amdgcn_rcpf(1.f + __expf(-aR[i]));
      const float zg = __builtin_amdgcn_rcpf(1.f + __expf(-aZ[i]));
      const float na = aNx2[i] + rg * aNh2[i];
      const float e2 = __expf(2.f * na);
      const float ng = 1.f - 2.f * __builtin_amdgcn_rcpf(e2 + 1.f);
      const float ho = (float)h_old[i];
      const float hn = ng + zg * (ho - ng);
      hnv[i] = hn;
      nv4[i] = (h16)hn;
    }
    h_old = nv4;
  };

  auto mfma_all = [&](const f16x8* bh, const f16x8* bx,
                      f32x4& aR, f32x4& aZ, f32x4& aNh2, f32x4& aNx2) {
    aR = bR; aZ = bZ; aNh2 = bNh; aNx2 = bNx;
    #pragma unroll
    for (int ks = 0; ks < KSH; ++ks) {
      aR   = __builtin_amdgcn_mfma_f32_16x16x32_f16(wA[0][ks], bh[ks], aR, 0, 0, 0);
      aZ   = __builtin_amdgcn_mfma_f32_16x16x32_f16(wA[1][ks], bh[ks], aZ, 0, 0, 0);
      aNh2 = __builtin_amdgcn_mfma_f32_16x16x32_f16(wA[2][ks], bh[ks], aNh2, 0, 0, 0);
    }
    #pragma unroll
    for (int ks = 0; ks < KSX; ++ks) {
      aR   = __builtin_amdgcn_mfma_f32_16x16x32_f16(wB[0][ks], bx[ks], aR, 0, 0, 0);
      aZ   = __builtin_amdgcn_mfma_f32_16x16x32_f16(wB[1][ks], bx[ks], aZ, 0, 0, 0);
      aNx2 = __builtin_amdgcn_mfma_f32_16x16x32_f16(wB[2][ks], bx[ks], aNx2, 0, 0, 0);
    }
  };

  if constexpr (PROD) {
    auto pstep = [&](int t, int cur, f16x2& s_use, f16x2& s_load) {
      f16x8 bh[KSH], bx[KSX];
      #pragma unroll
      for (int ks = 0; ks < KSH; ++ks) bh[ks] = *(const f16x8*)&hx[cur][lr][ks * 32 + q * 8];
      #pragma unroll
      for (int ks = 0; ks < KSX; ++ks) bx[ks] = *(const f16x8*)&hx[cur][lr][H_DIM + ks * 32 + q * 8];

      {  // prefetch x(t+2), 2-deep
        const int tt = (t + 2 < T_SEQ) ? t + 2 : T_SEQ - 1;
        const float2 v = *(const float2*)(xin + ((size_t)(r0 + sr) * T_SEQ + tt) * 64 + si * 2);
        s_load[0] = (h16)v.x; s_load[1] = (h16)v.y;
      }

      f32x4 aR, aZ, aNh2, aNx2;
      mfma_all(bh, bx, aR, aZ, aNh2, aNx2);

      f16x4 nv4; float hnv[4];
      gates(aR, aZ, aNx2, aNh2, nv4, hnv);

      u64 bits; __builtin_memcpy(&bits, &nv4, 8);
      __hip_atomic_store(&h1q[((size_t)t * B_SZ + r0 + lr) * 32 + (j0 >> 2)], bits,
                         __ATOMIC_RELAXED, __HIP_MEMORY_SCOPE_AGENT);

      *(f16x4*)&hx[cur ^ 1][lr][j0] = nv4;
      *(f16x2*)&hx[cur ^ 1][sr][H_DIM + si * 2] = s_use;

      if ((t & (CHUNK - 1)) == CHUNK - 1) __threadfence();  // once per chunk
      __syncthreads();
      if (((t & (CHUNK - 1)) == CHUNK - 1) && tid == 0)
        __hip_atomic_store(flag, (t + 1) / CHUNK, __ATOMIC_RELEASE, __HIP_MEMORY_SCOPE_AGENT);
    };

    #pragma unroll 1
    for (int t = 0; t < T_SEQ; t += 2) {
      pstep(t,     0, sA, sB);
      pstep(t + 1, 1, sB, sA);
    }
  } else {
    auto cstep = [&](int t, int cur, f16x4& s_use, f16x4& s_load) {
      f16x8 bh[KSH], bx[KSX];
      #pragma unroll
      for (int ks = 0; ks < KSH; ++ks) bh[ks] = *(const f16x8*)&hx[cur][lr][ks * 32 + q * 8];
      #pragma unroll
      for (int ks = 0; ks < KSX; ++ks) bx[ks] = *(const f16x8*)&hx[cur][lr][H_DIM + ks * 32 + q * 8];

      // prefetch h1(t+2): chunk-gated spin only at 32-step boundaries
      if (t + 2 < T_SEQ) {
        if (((t + 2) & (CHUNK - 1)) == 0) {
          const int need = (t + 2) / CHUNK + 1;
          while (__hip_atomic_load(flag, __ATOMIC_ACQUIRE, __HIP_MEMORY_SCOPE_AGENT) < need)
            __builtin_amdgcn_s_sleep(2);
        }
        load_h1(t + 2, s_load);
      }

      f32x4 aR, aZ, aNh2, aNx2;
      mfma_all(bh, bx, aR, aZ, aNh2, aNx2);

      f16x4 nv4; float hnv[4];
      gates(aR, aZ, aNx2, aNh2, nv4, hnv);

      *(f16x4*)&hx[cur ^ 1][lr][j0] = nv4;
      if (t + 1 < T_SEQ) *(f16x4*)&hx[cur ^ 1][sr][H_DIM + si * 4] = s_use;

      if (t == T_SEQ - 1) {
        // ---- fused FC head: fc2(BN(relu(fc1(h2)))) for this block's 16 rows
        float* h2f = headbuf;              // [16][128]
        float* act = headbuf + 16 * 128;   // [16][64]
        #pragma unroll
        for (int i = 0; i < 4; ++i) h2f[lr * 128 + j0 + i] = hnv[i];
        __syncthreads();
        {
          const int row = tid >> 5;
          const float* hr = &h2f[row * 128];
          #pragma unroll
          for (int half = 0; half < 2; ++half) {
            const int j = (tid & 31) + half * 32;
            float s = fc1_b[j];
            const float4* wr = (const float4*)(fc1_w + (size_t)j * H_DIM);
            #pragma unroll
            for (int k4 = 0; k4 < H_DIM / 4; ++k4) {
              const float4 w = wr[k4];
              const float4 h = ((const float4*)hr)[k4];
              s += w.x * h.x + w.y * h.y + w.z * h.z + w.w * h.w;
            }
            s = fmaxf(s, 0.f);
            s = (s - mean[j]) * rsqrtf(var[j] + 1e-5f) * gamma[j] + beta[j];
            act[row * 64 + j] = s;
          }
        }
        __syncthreads();
        if (tid < 32) {
          const int r = tid >> 1, o = tid & 1;
          float s = fc2_b[o];
          #pragma unroll
          for (int k = 0; k < 64; ++k) s += fc2_w[(size_t)o * 64 + k] * act[r * 64 + k];
          out[(size_t)(r0 + r) * 2 + o] = s;
        }
      }
      __syncthreads();
    };

    #pragma unroll 1
    for (int t = 0; t < T_SEQ; t += 2) {
      cstep(t,     0, cA, cB);
      cstep(t + 1, 1, cB, cA);
    }
  }
}

__global__ __launch_bounds__(NT, 1)   // 1 block/CU: producers & consumers on distinct CUs
void gru_fused(const float* __restrict__ x,
               const float* __restrict__ w_ih0, const float* __restrict__ w_hh0,
               const float* __restrict__ b_ih0, const float* __restrict__ b_hh0,
               const float* __restrict__ w_ih1, const float* __restrict__ w_hh1,
               const float* __restrict__ b_ih1, const float* __restrict__ b_hh1,
               u64* __restrict__ h1q, int* __restrict__ flags,
               const float* __restrict__ fc1_w, const float* __restrict__ fc1_b,
               const float* __restrict__ fc2_w, const float* __restrict__ fc2_b,
               const float* __restrict__ gamma, const float* __restrict__ beta,
               const float* __restrict__ mean,  const float* __restrict__ var,
               float* __restrict__ out)
{
  __shared__ __align__(16) char smem[(size_t)2 * ROWS * (H_DIM + H_DIM + 8) * sizeof(h16)];
  __shared__ __align__(16) float headbuf[16 * 128 + 16 * 64];
  const int bid = blockIdx.x;
  if (bid < NGRP)
    gru_body<64, true>(smem, headbuf, x, w_ih0, w_hh0, b_ih0, b_hh0, h1q, &flags[bid],
                       nullptr, nullptr, nullptr, nullptr, nullptr, nullptr, nullptr, nullptr,
                       nullptr, bid);
  else
    gru_body<128, false>(smem, headbuf, nullptr, w_ih1, w_hh1, b_ih1, b_hh1, h1q,
                         &flags[bid - NGRP], fc1_w, fc1_b, fc2_w, fc2_b, gamma, beta,
                         mean, var, out, bid - NGRP);
}

} // namespace

extern "C" void kernel_launch(void* const* d_in, const int* in_sizes, int n_in,
                              void* d_out, int out_size, void* d_ws, size_t ws_size,
                              hipStream_t stream) {
  const float* x     = (const float*)d_in[0];
  const float* w_ih0 = (const float*)d_in[1];
  const float* w_hh0 = (const float*)d_in[2];
  const float* b_ih0 = (const float*)d_in[3];
  const float* b_hh0 = (const float*)d_in[4];
  const float* w_ih1 = (const float*)d_in[5];
  const float* w_hh1 = (const float*)d_in[6];
  const float* b_ih1 = (const float*)d_in[7];
  const float* b_hh1 = (const float*)d_in[8];
  const float* fc1_w = (const float*)d_in[9];
  const float* fc1_b = (const float*)d_in[10];
  const float* fc2_w = (const float*)d_in[11];
  const float* fc2_b = (const float*)d_in[12];
  const float* gamma = (const float*)d_in[13];
  const float* beta  = (const float*)d_in[14];
  const float* mean  = (const float*)d_in[15];
  const float* var   = (const float*)d_in[16];
  float* out = (float*)d_out;

  char* ws = (char*)d_ws;
  const size_t h1_bytes = (size_t)T_SEQ * B_SZ * H_DIM * sizeof(h16);      // 134 MB
  const size_t fl_bytes = (size_t)NGRP * sizeof(int);
  if (ws_size < h1_bytes + fl_bytes) return;  // fail visibly

  u64* h1q   = (u64*)ws;
  int* flags = (int*)(ws + h1_bytes);

  hipMemsetAsync(flags, 0, fl_bytes, stream);   // flags start at 0 each replay
  gru_fused<<<dim3(2 * NGRP), dim3(NT), 0, stream>>>(
      x, w_ih0, w_hh0, b_ih0, b_hh0, w_ih1, w_hh1, b_ih1, b_hh1, h1q, flags,
      fc1_w, fc1_b, fc2_w, fc2_b, gamma, beta, mean, var, out);
}